// Round 2
// 553.437 us; speedup vs baseline: 1.2778x; 1.2778x over previous
//
#include <hip/hip_runtime.h>
#include <cstdint>

// BDHW_LSTM R5: R4 (single-barrier recurrence, register-resident x frags)
// + bufC double-buffer fixing the flush/write race.
//  K0 k_xpose: img f32 [b][d][hh][w] -> XT fp16 [b][hh][w][d]            (32 MB ws)
//  K1 k_hrec : horizontal biLSTM. Per step: acc = accx(precomputed x*Wih+bias)
//              + h*Whh (2 MFMA/p from LDS double-buffered h). ONE raw s_barrier
//              per step (lgkmcnt only, NO vmcnt drain -> x prefetch latency of
//              step s+2 hides under step s+1). HOUT fp16 [hh][b][w][128].
//  K2 k_vrec : vertical biLSTM, same structure, K=128 x-part in registers,
//              writes final out f32 [b][ch][hh][w] via float4.
// A-frag (16x16x32 f16): lane l holds (m=l&15, k-octet=l>>4); x frags loaded
// per-wave from global with row clamp (l&7) -> rows 8..15 garbage, discarded.
// C layout (m89): col=lane&15, row=(lane>>4)*4+reg. Wave wv owns gates
// wv*16+col for p=i,f,g,o -> nonlinearity fully in-lane. Gate order i,f,g,o.
// bufC is double-buffered by 16-step group ((s>>4)&1): flush of group g^1
// overlaps writes to group g with disjoint addresses; group-g flush reads are
// lgkmcnt-drained at that step's barrier, 16 steps before g is re-written.

typedef _Float16 half8_t __attribute__((ext_vector_type(8)));
typedef float f32x4_t __attribute__((ext_vector_type(4)));

__device__ __forceinline__ float sigm(float x) {
    // 1/(1+e^-x) via exp2 + single-inst rcp (err ~1e-7, << fp16 input noise)
    return __builtin_amdgcn_rcpf(1.0f + __builtin_amdgcn_exp2f(x * -1.44269504f));
}
__device__ __forceinline__ float tanh_(float x) {
    // tanh = 1 - 2/(1+e^{2x})
    return 1.0f - 2.0f * __builtin_amdgcn_rcpf(1.0f + __builtin_amdgcn_exp2f(x * 2.88539008f));
}

// Raw workgroup barrier: LDS ordering only (lgkmcnt), NO vmcnt(0) drain.
// Pattern verified on gfx950 by the 8-phase GEMM template (m194-m201).
__device__ __forceinline__ void block_sync() {
    asm volatile("s_waitcnt lgkmcnt(0)" ::: "memory");
    __builtin_amdgcn_s_barrier();
    asm volatile("" ::: "memory");
}

__device__ __forceinline__ half8_t load_w8(const float* p) {
    const float4 a = *(const float4*)p;
    const float4 b = *(const float4*)(p + 4);
    half8_t r;
    r[0] = (_Float16)a.x; r[1] = (_Float16)a.y; r[2] = (_Float16)a.z; r[3] = (_Float16)a.w;
    r[4] = (_Float16)b.x; r[5] = (_Float16)b.y; r[6] = (_Float16)b.z; r[7] = (_Float16)b.w;
    return r;
}

// chunk flush: bufC group fp16 [16w][8m][64gate] -> hout [hh][b][w][128] (+dir*64)
__device__ __forceinline__ void flush_chunk(const _Float16* bufCg, _Float16* hout,
                                            int hh0, int b, int dir, int wc0, int t)
{
    const int fm = t >> 5, fwi = (t >> 1) & 15, fhal = t & 1;
    const _Float16* src = bufCg + (fwi * 8 + fm) * 64 + fhal * 32;
    _Float16* dst = hout + ((size_t)(((hh0 + fm) * 8 + b) * 256 + wc0 + fwi) << 7)
                  + dir * 64 + fhal * 32;
    #pragma unroll
    for (int i = 0; i < 4; ++i)
        *(half8_t*)(dst + i * 8) = *(const half8_t*)(src + i * 8);
}

// ---------------- K0: img transpose to fp16 [b][hh][w][d] ----------------
__global__ __launch_bounds__(256) void k_xpose(const float* __restrict__ img, _Float16* __restrict__ xt)
{
    __shared__ float Ts[64 * 65];
    const int t  = threadIdx.x;
    const int wt = blockIdx.x & 3;
    const int hh = (blockIdx.x >> 2) & 127;
    const int b  = blockIdx.x >> 9;
    {
        const int d  = t >> 2;
        const int wq = (t & 3) * 16;
        const float* p = img + (((size_t)(b * 64 + d) * 128 + hh) * 256 + wt * 64 + wq);
        #pragma unroll
        for (int i = 0; i < 4; ++i) {
            const float4 v = *(const float4*)(p + i * 4);
            Ts[d * 65 + wq + i * 4 + 0] = v.x;
            Ts[d * 65 + wq + i * 4 + 1] = v.y;
            Ts[d * 65 + wq + i * 4 + 2] = v.z;
            Ts[d * 65 + wq + i * 4 + 3] = v.w;
        }
    }
    __syncthreads();
    const int wl = t >> 2;
    const int dq = (t & 3) * 16;
    half8_t o0, o1;
    #pragma unroll
    for (int i = 0; i < 8; ++i) o0[i] = (_Float16)Ts[(dq + i) * 65 + wl];
    #pragma unroll
    for (int i = 0; i < 8; ++i) o1[i] = (_Float16)Ts[(dq + 8 + i) * 65 + wl];
    _Float16* dst = xt + ((size_t)((b * 128 + hh) * 256 + wt * 64 + wl) << 6) + dq;
    *(half8_t*)(dst)     = o0;
    *(half8_t*)(dst + 8) = o1;
}

// ---------------- K1: horizontal biLSTM ----------------
// grid 256 = (b(8) x hh-octet(16))(128) x dir(2); block 256 (4 waves).
__global__ __launch_bounds__(256) void k_hrec(
    const _Float16* __restrict__ xt,
    const float* __restrict__ wihf, const float* __restrict__ whhf,
    const float* __restrict__ bif,  const float* __restrict__ bhf,
    const float* __restrict__ wihb, const float* __restrict__ whhb,
    const float* __restrict__ bib,  const float* __restrict__ bhb,
    _Float16* __restrict__ hout)
{
    __shared__ __align__(16) _Float16 Hbuf[2 * 1024];        // h double buffer: 2 x 2 ktiles
    __shared__ __align__(16) _Float16 bufC[2 * 16 * 8 * 64]; // 32 KB retime, dbl-buffered
    const int t   = threadIdx.x;
    const int dir = blockIdx.x & 1;
    const int g   = blockIdx.x >> 1;
    const int b   = g & 7;
    const int hh0 = (g >> 3) * 8;
    const int wv  = t >> 6;
    const int l   = t & 63;
    const float* Wih = dir ? wihb : wihf;
    const float* Whh = dir ? whhb : whhf;
    const float* Bi  = dir ? bib  : bif;
    const float* Bh  = dir ? bhb  : bhf;

    // B-frags: Bf[p][kt], gate = p*64 + wv*16 + (l&15), k = kt*32 + (l>>4)*8 + j
    half8_t Bf[4][4];
    float bias[4];
    #pragma unroll
    for (int p = 0; p < 4; ++p) {
        const int gate = p * 64 + wv * 16 + (l & 15);
        bias[p] = Bi[gate] + Bh[gate];
        #pragma unroll
        for (int kt = 0; kt < 4; ++kt) {
            const int k0 = kt * 32 + (l >> 4) * 8;
            const float* src = (kt < 2) ? (Wih + gate * 64 + k0) : (Whh + gate * 64 + (k0 - 64));
            Bf[p][kt] = load_w8(src);
        }
    }
    for (int i = t; i < 2048; i += 256) Hbuf[i] = (_Float16)0.0f;  // incl. pad rows 8..15

    // per-lane x A-frag pointer: row clamped to valid octet (rows 8..15 mirror 0..7,
    // garbage lands in discarded C rows; stays finite, no OOB)
    const int mrow = l & 7;
    const int ko   = l >> 4;
    const _Float16* xb = xt + (((size_t)(b * 128 + hh0 + mrow) * 256) << 6) + ko * 8;

    float c_[4] = {0.f, 0.f, 0.f, 0.f};
    const int col = l & 15;
    const int rq  = l >> 4;
    const int jg  = wv * 16 + col;
    const int hpos = (jg >> 5) * 512 + (((jg >> 3) & 3) * 16) * 8 + (jg & 7);

    // prologue: x frags for steps 0 and 1; accx = bias + x0*Wih
    const int wA = dir ? 255 : 0;
    const int wB = dir ? 254 : 1;
    half8_t xc0 = *(const half8_t*)(xb + (wA << 6));
    half8_t xc1 = *(const half8_t*)(xb + (wA << 6) + 32);
    half8_t xn0 = *(const half8_t*)(xb + (wB << 6));
    half8_t xn1 = *(const half8_t*)(xb + (wB << 6) + 32);
    f32x4_t accx[4];
    #pragma unroll
    for (int p = 0; p < 4; ++p) {
        f32x4_t a = {bias[p], bias[p], bias[p], bias[p]};
        a = __builtin_amdgcn_mfma_f32_16x16x32_f16(xc0, Bf[p][0], a, 0, 0, 0);
        a = __builtin_amdgcn_mfma_f32_16x16x32_f16(xc1, Bf[p][1], a, 0, 0, 0);
        accx[p] = a;
    }
    __syncthreads();

    for (int s = 0; s < 256; ++s) {
        const int grp = (s >> 4) & 1;   // bufC write group for this 16-step window
        if ((s & 15) == 0 && s > 0)     // flush previous 16-w chunk (other group)
            flush_chunk(bufC + (grp ^ 1) * 8192, hout, hh0, b, dir,
                        dir ? (256 - s) : (s - 16), t);

        const int rdo = (s & 1) << 10;
        const half8_t H0 = *(const half8_t*)(Hbuf + rdo + l * 8);
        const half8_t H1 = *(const half8_t*)(Hbuf + rdo + 512 + l * 8);
        f32x4_t acc[4];
        #pragma unroll
        for (int p = 0; p < 4; ++p) {
            f32x4_t a = accx[p];
            a = __builtin_amdgcn_mfma_f32_16x16x32_f16(H0, Bf[p][2], a, 0, 0, 0);
            a = __builtin_amdgcn_mfma_f32_16x16x32_f16(H1, Bf[p][3], a, 0, 0, 0);
            acc[p] = a;
        }
        // pipeline next step's x part (MFMA pipe overlaps gate-math VALU below);
        // then issue x loads for s+2 (full step of latency cover, no vmcnt drain)
        if (s + 1 < 256) {
            #pragma unroll
            for (int p = 0; p < 4; ++p) {
                f32x4_t a = {bias[p], bias[p], bias[p], bias[p]};
                a = __builtin_amdgcn_mfma_f32_16x16x32_f16(xn0, Bf[p][0], a, 0, 0, 0);
                a = __builtin_amdgcn_mfma_f32_16x16x32_f16(xn1, Bf[p][1], a, 0, 0, 0);
                accx[p] = a;
            }
            if (s + 2 < 256) {
                const int w2 = dir ? (253 - s) : (s + 2);
                xn0 = *(const half8_t*)(xb + (w2 << 6));
                xn1 = *(const half8_t*)(xb + (w2 << 6) + 32);
            }
        }
        float hv[4];
        #pragma unroll
        for (int r = 0; r < 4; ++r) {
            const float gi = acc[0][r];
            const float gf = acc[1][r];
            const float gg = acc[2][r];
            const float go = acc[3][r];
            c_[r] = sigm(gf) * c_[r] + sigm(gi) * tanh_(gg);
            hv[r] = sigm(go) * tanh_(c_[r]);
        }
        const int w   = dir ? (255 - s) : s;
        const int wro = ((s + 1) & 1) << 10;
        if (rq < 2) {   // active rows 0..7: h_{s+1} -> other buffer + retime bufC
            #pragma unroll
            for (int r = 0; r < 4; ++r) {
                const int m = rq * 4 + r;
                Hbuf[wro + hpos + m * 8] = (_Float16)hv[r];
                bufC[grp * 8192 + ((w & 15) * 8 + m) * 64 + jg] = (_Float16)hv[r];
            }
        }
        block_sync();   // single barrier: h buffers alternate; bufC group reused 16 steps later
    }
    flush_chunk(bufC + 8192, hout, hh0, b, dir, dir ? 0 : 240, t);  // last group = ((255>>4)&1)=1
}

// ---------------- K2: vertical biLSTM + direct output ----------------
// grid 512 = (b(8) x w-octet(32))(256) x dir(2); block 256 (4 waves).
__global__ __launch_bounds__(256) void k_vrec(
    const _Float16* __restrict__ hout,
    const float* __restrict__ wihf, const float* __restrict__ whhf,
    const float* __restrict__ bif,  const float* __restrict__ bhf,
    const float* __restrict__ wihb, const float* __restrict__ whhb,
    const float* __restrict__ bib,  const float* __restrict__ bhb,
    float* __restrict__ outp)
{
    __shared__ __align__(16) _Float16 Hbuf[2 * 1024];   // h double buffer
    const int t   = threadIdx.x;
    const int dir = blockIdx.x & 1;
    const int g   = blockIdx.x >> 1;
    const int b   = g & 7;
    const int w0  = (g >> 3) * 8;
    const int wv  = t >> 6;
    const int l   = t & 63;
    const float* Wih = dir ? wihb : wihf;
    const float* Whh = dir ? whhb : whhf;
    const float* Bi  = dir ? bib  : bif;
    const float* Bh  = dir ? bhb  : bhf;

    half8_t Bf[4][6];
    float bias[4];
    #pragma unroll
    for (int p = 0; p < 4; ++p) {
        const int gate = p * 64 + wv * 16 + (l & 15);
        bias[p] = Bi[gate] + Bh[gate];
        #pragma unroll
        for (int kt = 0; kt < 6; ++kt) {
            const int k0 = kt * 32 + (l >> 4) * 8;
            const float* src = (kt < 4) ? (Wih + gate * 128 + k0) : (Whh + gate * 64 + (k0 - 128));
            Bf[p][kt] = load_w8(src);
        }
    }
    for (int i = t; i < 2048; i += 256) Hbuf[i] = (_Float16)0.0f;

    const int mrow = l & 7;
    const int ko   = l >> 4;
    const _Float16* xb = hout + ((size_t)(b * 256 + w0 + mrow) << 7) + ko * 8;  // + (hh<<18) + kt*32

    float c_[4] = {0.f, 0.f, 0.f, 0.f};
    const int col = l & 15;
    const int rq  = l >> 4;
    const int jg  = wv * 16 + col;
    const int hpos = (jg >> 5) * 512 + (((jg >> 3) & 3) * 16) * 8 + (jg & 7);
    const int ch  = dir * 64 + jg;

    const int hA = dir ? 127 : 0;
    const int hB = dir ? 126 : 1;
    half8_t xc[4], xn[4];
    #pragma unroll
    for (int kt = 0; kt < 4; ++kt) {
        xc[kt] = *(const half8_t*)(xb + ((size_t)hA << 18) + kt * 32);
        xn[kt] = *(const half8_t*)(xb + ((size_t)hB << 18) + kt * 32);
    }
    f32x4_t accx[4];
    #pragma unroll
    for (int p = 0; p < 4; ++p) {
        f32x4_t a = {bias[p], bias[p], bias[p], bias[p]};
        #pragma unroll
        for (int kt = 0; kt < 4; ++kt)
            a = __builtin_amdgcn_mfma_f32_16x16x32_f16(xc[kt], Bf[p][kt], a, 0, 0, 0);
        accx[p] = a;
    }
    __syncthreads();

    for (int s = 0; s < 128; ++s) {
        const int rdo = (s & 1) << 10;
        const half8_t H0 = *(const half8_t*)(Hbuf + rdo + l * 8);
        const half8_t H1 = *(const half8_t*)(Hbuf + rdo + 512 + l * 8);
        f32x4_t acc[4];
        #pragma unroll
        for (int p = 0; p < 4; ++p) {
            f32x4_t a = accx[p];
            a = __builtin_amdgcn_mfma_f32_16x16x32_f16(H0, Bf[p][4], a, 0, 0, 0);
            a = __builtin_amdgcn_mfma_f32_16x16x32_f16(H1, Bf[p][5], a, 0, 0, 0);
            acc[p] = a;
        }
        if (s + 1 < 128) {
            #pragma unroll
            for (int p = 0; p < 4; ++p) {
                f32x4_t a = {bias[p], bias[p], bias[p], bias[p]};
                #pragma unroll
                for (int kt = 0; kt < 4; ++kt)
                    a = __builtin_amdgcn_mfma_f32_16x16x32_f16(xn[kt], Bf[p][kt], a, 0, 0, 0);
                accx[p] = a;
            }
            if (s + 2 < 128) {
                const int h2 = dir ? (125 - s) : (s + 2);
                #pragma unroll
                for (int kt = 0; kt < 4; ++kt)
                    xn[kt] = *(const half8_t*)(xb + ((size_t)h2 << 18) + kt * 32);
            }
        }
        float hv[4];
        #pragma unroll
        for (int r = 0; r < 4; ++r) {
            const float gi = acc[0][r];
            const float gf = acc[1][r];
            const float gg = acc[2][r];
            const float go = acc[3][r];
            c_[r] = sigm(gf) * c_[r] + sigm(gi) * tanh_(gg);
            hv[r] = sigm(go) * tanh_(c_[r]);
        }
        const int hh  = dir ? (127 - s) : s;
        const int wro = ((s + 1) & 1) << 10;
        if (rq < 2) {
            float4 v = make_float4(hv[0], hv[1], hv[2], hv[3]);
            *(float4*)(outp + ((size_t)(b * 128 + ch) * 128 + hh) * 256 + w0 + rq * 4) = v;
            #pragma unroll
            for (int r = 0; r < 4; ++r)
                Hbuf[wro + hpos + (rq * 4 + r) * 8] = (_Float16)hv[r];
        }
        block_sync();
    }
}

extern "C" void kernel_launch(void* const* d_in, const int* in_sizes, int n_in,
                              void* d_out, int out_size, void* d_ws, size_t ws_size,
                              hipStream_t stream)
{
    const float* img   = (const float*)d_in[0];
    const float* hWihF = (const float*)d_in[1];
    const float* hWhhF = (const float*)d_in[2];
    const float* hBiF  = (const float*)d_in[3];
    const float* hBhF  = (const float*)d_in[4];
    const float* hWihB = (const float*)d_in[5];
    const float* hWhhB = (const float*)d_in[6];
    const float* hBiB  = (const float*)d_in[7];
    const float* hBhB  = (const float*)d_in[8];
    const float* vWihF = (const float*)d_in[9];
    const float* vWhhF = (const float*)d_in[10];
    const float* vBiF  = (const float*)d_in[11];
    const float* vBhF  = (const float*)d_in[12];
    const float* vWihB = (const float*)d_in[13];
    const float* vWhhB = (const float*)d_in[14];
    const float* vBiB  = (const float*)d_in[15];
    const float* vBhB  = (const float*)d_in[16];

    _Float16* XT   = (_Float16*)d_ws;                             // 32 MB
    _Float16* HOUT = (_Float16*)((char*)d_ws + (size_t)33554432); // 64 MB

    k_xpose<<<4096, 256, 0, stream>>>(img, XT);
    k_hrec<<<256, 256, 0, stream>>>(XT, hWihF, hWhhF, hBiF, hBhF,
                                    hWihB, hWhhB, hBiB, hBhB, HOUT);
    k_vrec<<<512, 256, 0, stream>>>(HOUT, vWihF, vWhhF, vBiF, vBhF,
                                    vWihB, vWhhB, vBiB, vBhB, (float*)d_out);

    (void)in_sizes; (void)n_in; (void)out_size; (void)ws_size;
}

// Round 3
// 522.111 us; speedup vs baseline: 1.3545x; 1.0600x over previous
//
#include <hip/hip_runtime.h>
#include <cstdint>

// BDHW_LSTM R6: R5 + (a) vrec output LDS-retimed (kills per-step scattered
// global store whose in-order vmcnt retirement entangled the x-load wait),
// (b) step loop unrolled x2 with per-parity x register sets -> 2-step
// prefetch distance (full HBM-latency cover), (c) stores only at 16-step
// flushes, always issued NEWEST relative to the loads waited on.
//  K0 k_xpose: img f32 [b][d][hh][w] -> XT fp16 [b][hh][w][d]        (32 MB ws)
//  K1 k_hrec : horizontal biLSTM, 1 raw barrier/step. HOUT fp16 [hh][b][w][128].
//  K2 k_vrec : vertical biLSTM, 1 raw barrier/step, OutS retime -> out f32.
// A-frag (16x16x32 f16): lane l holds (m=l&15, k-octet=l>>4); x frags loaded
// per-wave from global with row clamp (l&7) -> rows 8..15 garbage, discarded.
// C layout (m89): col=lane&15, row=(lane>>4)*4+reg. Wave wv owns gates
// wv*16+col for p=i,f,g,o. Gate order i,f,g,o (PyTorch).

typedef _Float16 half8_t __attribute__((ext_vector_type(8)));
typedef float f32x4_t __attribute__((ext_vector_type(4)));

__device__ __forceinline__ float sigm(float x) {
    return __builtin_amdgcn_rcpf(1.0f + __builtin_amdgcn_exp2f(x * -1.44269504f));
}
__device__ __forceinline__ float tanh_(float x) {
    return 1.0f - 2.0f * __builtin_amdgcn_rcpf(1.0f + __builtin_amdgcn_exp2f(x * 2.88539008f));
}

// Raw workgroup barrier: LDS ordering only (lgkmcnt), NO vmcnt(0) drain.
__device__ __forceinline__ void block_sync() {
    asm volatile("s_waitcnt lgkmcnt(0)" ::: "memory");
    __builtin_amdgcn_s_barrier();
    asm volatile("" ::: "memory");
}

__device__ __forceinline__ half8_t load_w8(const float* p) {
    const float4 a = *(const float4*)p;
    const float4 b = *(const float4*)(p + 4);
    half8_t r;
    r[0] = (_Float16)a.x; r[1] = (_Float16)a.y; r[2] = (_Float16)a.z; r[3] = (_Float16)a.w;
    r[4] = (_Float16)b.x; r[5] = (_Float16)b.y; r[6] = (_Float16)b.z; r[7] = (_Float16)b.w;
    return r;
}

// hrec chunk flush: bufC group fp16 [16w][8m][64gate] -> hout [hh][b][w][128]
__device__ __forceinline__ void flush_chunk(const _Float16* bufCg, _Float16* hout,
                                            int hh0, int b, int dir, int wc0, int t)
{
    const int fm = t >> 5, fwi = (t >> 1) & 15, fhal = t & 1;
    const _Float16* src = bufCg + (fwi * 8 + fm) * 64 + fhal * 32;
    _Float16* dst = hout + ((size_t)(((hh0 + fm) * 8 + b) * 256 + wc0 + fwi) << 7)
                  + dir * 64 + fhal * 32;
    #pragma unroll
    for (int i = 0; i < 4; ++i)
        *(half8_t*)(dst + i * 8) = *(const half8_t*)(src + i * 8);
}

// vrec chunk flush: OutS group f32 [16hh][8w][64ch] -> out f32 [b][ch][hh][w]
__device__ __forceinline__ void vflush(const float* Og, float* outp,
                                       int b, int dir, int w0, int hh0c, int t)
{
    const int ch = t & 63;
    const int hq = t >> 6;            // 0..3
    #pragma unroll
    for (int i = 0; i < 4; ++i) {
        const int hh = hq * 4 + i;
        float v[8];
        #pragma unroll
        for (int w = 0; w < 8; ++w) v[w] = Og[(hh * 8 + w) * 64 + ch];
        float4 a = make_float4(v[0], v[1], v[2], v[3]);
        float4 c = make_float4(v[4], v[5], v[6], v[7]);
        float* dst = outp + ((size_t)(b * 128 + dir * 64 + ch) * 128 + hh0c + hh) * 256 + w0;
        *(float4*)dst = a;
        *(float4*)(dst + 4) = c;
    }
}

// ---------------- K0: img transpose to fp16 [b][hh][w][d] ----------------
__global__ __launch_bounds__(256) void k_xpose(const float* __restrict__ img, _Float16* __restrict__ xt)
{
    __shared__ float Ts[64 * 65];
    const int t  = threadIdx.x;
    const int wt = blockIdx.x & 3;
    const int hh = (blockIdx.x >> 2) & 127;
    const int b  = blockIdx.x >> 9;
    {
        const int d  = t >> 2;
        const int wq = (t & 3) * 16;
        const float* p = img + (((size_t)(b * 64 + d) * 128 + hh) * 256 + wt * 64 + wq);
        #pragma unroll
        for (int i = 0; i < 4; ++i) {
            const float4 v = *(const float4*)(p + i * 4);
            Ts[d * 65 + wq + i * 4 + 0] = v.x;
            Ts[d * 65 + wq + i * 4 + 1] = v.y;
            Ts[d * 65 + wq + i * 4 + 2] = v.z;
            Ts[d * 65 + wq + i * 4 + 3] = v.w;
        }
    }
    __syncthreads();
    const int wl = t >> 2;
    const int dq = (t & 3) * 16;
    half8_t o0, o1;
    #pragma unroll
    for (int i = 0; i < 8; ++i) o0[i] = (_Float16)Ts[(dq + i) * 65 + wl];
    #pragma unroll
    for (int i = 0; i < 8; ++i) o1[i] = (_Float16)Ts[(dq + 8 + i) * 65 + wl];
    _Float16* dst = xt + ((size_t)((b * 128 + hh) * 256 + wt * 64 + wl) << 6) + dq;
    *(half8_t*)(dst)     = o0;
    *(half8_t*)(dst + 8) = o1;
}

// ---------------- K1: horizontal biLSTM ----------------
// grid 256 = (b(8) x hh-octet(16))(128) x dir(2); block 256 (4 waves).
__global__ __launch_bounds__(256) void k_hrec(
    const _Float16* __restrict__ xt,
    const float* __restrict__ wihf, const float* __restrict__ whhf,
    const float* __restrict__ bif,  const float* __restrict__ bhf,
    const float* __restrict__ wihb, const float* __restrict__ whhb,
    const float* __restrict__ bib,  const float* __restrict__ bhb,
    _Float16* __restrict__ hout)
{
    __shared__ __align__(16) _Float16 Hbuf[2 * 1024];        // h double buffer
    __shared__ __align__(16) _Float16 bufC[2 * 8192];        // 32 KB retime, dbl grp
    const int t   = threadIdx.x;
    const int dir = blockIdx.x & 1;
    const int g   = blockIdx.x >> 1;
    const int b   = g & 7;
    const int hh0 = (g >> 3) * 8;
    const int wv  = t >> 6;
    const int l   = t & 63;
    const float* Wih = dir ? wihb : wihf;
    const float* Whh = dir ? whhb : whhf;
    const float* Bi  = dir ? bib  : bif;
    const float* Bh  = dir ? bhb  : bhf;

    half8_t Bf[4][4];
    float bias[4];
    #pragma unroll
    for (int p = 0; p < 4; ++p) {
        const int gate = p * 64 + wv * 16 + (l & 15);
        bias[p] = Bi[gate] + Bh[gate];
        #pragma unroll
        for (int kt = 0; kt < 4; ++kt) {
            const int k0 = kt * 32 + (l >> 4) * 8;
            const float* src = (kt < 2) ? (Wih + gate * 64 + k0) : (Whh + gate * 64 + (k0 - 64));
            Bf[p][kt] = load_w8(src);
        }
    }
    for (int i = t; i < 2048; i += 256) Hbuf[i] = (_Float16)0.0f;

    const int mrow = l & 7;
    const int ko   = l >> 4;
    const _Float16* xb = xt + (((size_t)(b * 128 + hh0 + mrow) * 256) << 6) + ko * 8;

    float c_[4] = {0.f, 0.f, 0.f, 0.f};
    const int col = l & 15;
    const int rq  = l >> 4;
    const int jg  = wv * 16 + col;
    const int hpos = (jg >> 5) * 512 + (((jg >> 3) & 3) * 16) * 8 + (jg & 7);

    // step->w with clamp (prefetch overshoot reads duplicate last col, discarded)
    auto wof = [&](int s) { int ss = s < 256 ? s : 255; return dir ? (255 - ss) : ss; };

    // prologue: xE=x(0), xO=x(1); accx for step0 from xE; reload xE<-x(2)
    half8_t xE0 = *(const half8_t*)(xb + (wof(0) << 6));
    half8_t xE1 = *(const half8_t*)(xb + (wof(0) << 6) + 32);
    half8_t xO0 = *(const half8_t*)(xb + (wof(1) << 6));
    half8_t xO1 = *(const half8_t*)(xb + (wof(1) << 6) + 32);
    f32x4_t accx[4];
    #pragma unroll
    for (int p = 0; p < 4; ++p) {
        f32x4_t a = {bias[p], bias[p], bias[p], bias[p]};
        a = __builtin_amdgcn_mfma_f32_16x16x32_f16(xE0, Bf[p][0], a, 0, 0, 0);
        a = __builtin_amdgcn_mfma_f32_16x16x32_f16(xE1, Bf[p][1], a, 0, 0, 0);
        accx[p] = a;
    }
    xE0 = *(const half8_t*)(xb + (wof(2) << 6));
    xE1 = *(const half8_t*)(xb + (wof(2) << 6) + 32);
    __syncthreads();

    // body(s): consumes xr (= x(s+1)) for next accx; reloads xr <- x(s+3).
    auto body = [&](int s, half8_t& xr0, half8_t& xr1) {
        const int grp = (s >> 4) & 1;
        if ((s & 15) == 0 && s > 0)
            flush_chunk(bufC + (grp ^ 1) * 8192, hout, hh0, b, dir,
                        dir ? (256 - s) : (s - 16), t);

        const int rdo = (s & 1) << 10;
        const half8_t H0 = *(const half8_t*)(Hbuf + rdo + l * 8);
        const half8_t H1 = *(const half8_t*)(Hbuf + rdo + 512 + l * 8);
        f32x4_t acc[4];
        #pragma unroll
        for (int p = 0; p < 4; ++p) {
            f32x4_t a = accx[p];
            a = __builtin_amdgcn_mfma_f32_16x16x32_f16(H0, Bf[p][2], a, 0, 0, 0);
            a = __builtin_amdgcn_mfma_f32_16x16x32_f16(H1, Bf[p][3], a, 0, 0, 0);
            acc[p] = a;
        }
        // next step's x part (shadow), then reload xr for s+3 (2-step cover)
        #pragma unroll
        for (int p = 0; p < 4; ++p) {
            f32x4_t a = {bias[p], bias[p], bias[p], bias[p]};
            a = __builtin_amdgcn_mfma_f32_16x16x32_f16(xr0, Bf[p][0], a, 0, 0, 0);
            a = __builtin_amdgcn_mfma_f32_16x16x32_f16(xr1, Bf[p][1], a, 0, 0, 0);
            accx[p] = a;
        }
        {
            const int wn = wof(s + 3);
            xr0 = *(const half8_t*)(xb + (wn << 6));
            xr1 = *(const half8_t*)(xb + (wn << 6) + 32);
        }
        float hv[4];
        #pragma unroll
        for (int r = 0; r < 4; ++r) {
            c_[r] = sigm(acc[1][r]) * c_[r] + sigm(acc[0][r]) * tanh_(acc[2][r]);
            hv[r] = sigm(acc[3][r]) * tanh_(c_[r]);
        }
        const int w   = wof(s);
        const int wro = ((s + 1) & 1) << 10;
        if (rq < 2) {
            #pragma unroll
            for (int r = 0; r < 4; ++r) {
                const int m = rq * 4 + r;
                Hbuf[wro + hpos + m * 8] = (_Float16)hv[r];
                bufC[grp * 8192 + ((w & 15) * 8 + m) * 64 + jg] = (_Float16)hv[r];
            }
        }
        block_sync();
    };

    for (int s2 = 0; s2 < 256; s2 += 2) {
        body(s2,     xO0, xO1);
        body(s2 + 1, xE0, xE1);
    }
    flush_chunk(bufC + 8192, hout, hh0, b, dir, dir ? 0 : 240, t);
}

// ---------------- K2: vertical biLSTM + LDS-retimed output ----------------
// grid 512 = (b(8) x w-octet(32))(256) x dir(2); block 256 (4 waves).
__global__ __launch_bounds__(256) void k_vrec(
    const _Float16* __restrict__ hout,
    const float* __restrict__ wihf, const float* __restrict__ whhf,
    const float* __restrict__ bif,  const float* __restrict__ bhf,
    const float* __restrict__ wihb, const float* __restrict__ whhb,
    const float* __restrict__ bib,  const float* __restrict__ bhb,
    float* __restrict__ outp)
{
    __shared__ __align__(16) _Float16 Hbuf[2 * 1024];   // 4 KB h double buffer
    __shared__ __align__(16) float OutS[2 * 16 * 8 * 64]; // 64 KB out retime, dbl grp
    const int t   = threadIdx.x;
    const int dir = blockIdx.x & 1;
    const int g   = blockIdx.x >> 1;
    const int b   = g & 7;
    const int w0  = (g >> 3) * 8;
    const int wv  = t >> 6;
    const int l   = t & 63;
    const float* Wih = dir ? wihb : wihf;
    const float* Whh = dir ? whhb : whhf;
    const float* Bi  = dir ? bib  : bif;
    const float* Bh  = dir ? bhb  : bhf;

    half8_t Bf[4][6];
    float bias[4];
    #pragma unroll
    for (int p = 0; p < 4; ++p) {
        const int gate = p * 64 + wv * 16 + (l & 15);
        bias[p] = Bi[gate] + Bh[gate];
        #pragma unroll
        for (int kt = 0; kt < 6; ++kt) {
            const int k0 = kt * 32 + (l >> 4) * 8;
            const float* src = (kt < 4) ? (Wih + gate * 128 + k0) : (Whh + gate * 64 + (k0 - 128));
            Bf[p][kt] = load_w8(src);
        }
    }
    for (int i = t; i < 2048; i += 256) Hbuf[i] = (_Float16)0.0f;

    const int mrow = l & 7;
    const int ko   = l >> 4;
    const _Float16* xb = hout + ((size_t)(b * 256 + w0 + mrow) << 7) + ko * 8;

    float c_[4] = {0.f, 0.f, 0.f, 0.f};
    const int col = l & 15;
    const int rq  = l >> 4;
    const int jg  = wv * 16 + col;
    const int hpos = (jg >> 5) * 512 + (((jg >> 3) & 3) * 16) * 8 + (jg & 7);

    auto hof = [&](int s) { int ss = s < 128 ? s : 127; return dir ? (127 - ss) : ss; };

    half8_t xE[4], xO[4];
    #pragma unroll
    for (int kt = 0; kt < 4; ++kt) {
        xE[kt] = *(const half8_t*)(xb + ((size_t)hof(0) << 18) + kt * 32);
        xO[kt] = *(const half8_t*)(xb + ((size_t)hof(1) << 18) + kt * 32);
    }
    f32x4_t accx[4];
    #pragma unroll
    for (int p = 0; p < 4; ++p) {
        f32x4_t a = {bias[p], bias[p], bias[p], bias[p]};
        #pragma unroll
        for (int kt = 0; kt < 4; ++kt)
            a = __builtin_amdgcn_mfma_f32_16x16x32_f16(xE[kt], Bf[p][kt], a, 0, 0, 0);
        accx[p] = a;
    }
    #pragma unroll
    for (int kt = 0; kt < 4; ++kt)
        xE[kt] = *(const half8_t*)(xb + ((size_t)hof(2) << 18) + kt * 32);
    __syncthreads();

    auto body = [&](int s, half8_t (&xr)[4]) {
        const int grp = (s >> 4) & 1;
        if ((s & 15) == 0 && s > 0)
            vflush(OutS + (grp ^ 1) * 8192, outp, b, dir, w0,
                   dir ? (128 - s) : (s - 16), t);

        const int rdo = (s & 1) << 10;
        const half8_t H0 = *(const half8_t*)(Hbuf + rdo + l * 8);
        const half8_t H1 = *(const half8_t*)(Hbuf + rdo + 512 + l * 8);
        f32x4_t acc[4];
        #pragma unroll
        for (int p = 0; p < 4; ++p) {
            f32x4_t a = accx[p];
            a = __builtin_amdgcn_mfma_f32_16x16x32_f16(H0, Bf[p][4], a, 0, 0, 0);
            a = __builtin_amdgcn_mfma_f32_16x16x32_f16(H1, Bf[p][5], a, 0, 0, 0);
            acc[p] = a;
        }
        #pragma unroll
        for (int p = 0; p < 4; ++p) {
            f32x4_t a = {bias[p], bias[p], bias[p], bias[p]};
            #pragma unroll
            for (int kt = 0; kt < 4; ++kt)
                a = __builtin_amdgcn_mfma_f32_16x16x32_f16(xr[kt], Bf[p][kt], a, 0, 0, 0);
            accx[p] = a;
        }
        {
            const int hn = hof(s + 3);
            #pragma unroll
            for (int kt = 0; kt < 4; ++kt)
                xr[kt] = *(const half8_t*)(xb + ((size_t)hn << 18) + kt * 32);
        }
        float hv[4];
        #pragma unroll
        for (int r = 0; r < 4; ++r) {
            c_[r] = sigm(acc[1][r]) * c_[r] + sigm(acc[0][r]) * tanh_(acc[2][r]);
            hv[r] = sigm(acc[3][r]) * tanh_(c_[r]);
        }
        const int hh  = hof(s);
        const int wro = ((s + 1) & 1) << 10;
        if (rq < 2) {
            #pragma unroll
            for (int r = 0; r < 4; ++r) {
                const int m = rq * 4 + r;
                Hbuf[wro + hpos + m * 8] = (_Float16)hv[r];
                OutS[grp * 8192 + ((hh & 15) * 8 + m) * 64 + jg] = hv[r];
            }
        }
        block_sync();
    };

    for (int s2 = 0; s2 < 128; s2 += 2) {
        body(s2,     xO);
        body(s2 + 1, xE);
    }
    vflush(OutS + 8192, outp, b, dir, w0, dir ? 0 : 112, t);
}

extern "C" void kernel_launch(void* const* d_in, const int* in_sizes, int n_in,
                              void* d_out, int out_size, void* d_ws, size_t ws_size,
                              hipStream_t stream)
{
    const float* img   = (const float*)d_in[0];
    const float* hWihF = (const float*)d_in[1];
    const float* hWhhF = (const float*)d_in[2];
    const float* hBiF  = (const float*)d_in[3];
    const float* hBhF  = (const float*)d_in[4];
    const float* hWihB = (const float*)d_in[5];
    const float* hWhhB = (const float*)d_in[6];
    const float* hBiB  = (const float*)d_in[7];
    const float* hBhB  = (const float*)d_in[8];
    const float* vWihF = (const float*)d_in[9];
    const float* vWhhF = (const float*)d_in[10];
    const float* vBiF  = (const float*)d_in[11];
    const float* vBhF  = (const float*)d_in[12];
    const float* vWihB = (const float*)d_in[13];
    const float* vWhhB = (const float*)d_in[14];
    const float* vBiB  = (const float*)d_in[15];
    const float* vBhB  = (const float*)d_in[16];

    _Float16* XT   = (_Float16*)d_ws;                             // 32 MB
    _Float16* HOUT = (_Float16*)((char*)d_ws + (size_t)33554432); // 64 MB

    k_xpose<<<4096, 256, 0, stream>>>(img, XT);
    k_hrec<<<256, 256, 0, stream>>>(XT, hWihF, hWhhF, hBiF, hBhF,
                                    hWihB, hWhhB, hBiB, hBhB, HOUT);
    k_vrec<<<512, 256, 0, stream>>>(HOUT, vWihF, vWhhF, vBiF, vBhF,
                                    vWihB, vWhhB, vBiB, vBhB, (float*)d_out);

    (void)in_sizes; (void)n_in; (void)out_size; (void)ws_size;
}

// Round 5
// 452.613 us; speedup vs baseline: 1.5624x; 1.1535x over previous
//
#include <hip/hip_runtime.h>
#include <cstdint>

// BDHW_LSTM R7b: resubmission of R7 (audited clean; prior run hit infra
// "container failed twice"). Attack VALU/TRANS issue waste:
//  - k_vrec: M=16 (16 w-rows per block), grid 256 (1 block/CU). All MFMA rows
//    and all 64 lanes' gate math valid -> per-CU issue per step halved.
//    OutS retime in 4-step groups (32 KB).
//  - k_hrec: lane compaction: after MFMA, shfl acc[p][2..3] from lo-half lanes
//    into hi-half lanes; every lane does gate math on 2 valid cells instead of
//    4 half-garbage -> halves the transcendental-heavy phase.
//  Everything else = R6: single lgkmcnt-only barrier/step, 2-step x prefetch,
//  16-step bufC retime (hrec).
// A-frag (16x16x32 f16): lane l holds (m=l&15, k-octet=l>>4).
// C layout (m89): col=lane&15, row=(lane>>4)*4+reg. Gate order i,f,g,o.

typedef _Float16 half8_t __attribute__((ext_vector_type(8)));
typedef float f32x4_t __attribute__((ext_vector_type(4)));

__device__ __forceinline__ float sigm(float x) {
    return __builtin_amdgcn_rcpf(1.0f + __builtin_amdgcn_exp2f(x * -1.44269504f));
}
__device__ __forceinline__ float tanh_(float x) {
    return 1.0f - 2.0f * __builtin_amdgcn_rcpf(1.0f + __builtin_amdgcn_exp2f(x * 2.88539008f));
}

// Raw workgroup barrier: LDS ordering only (lgkmcnt), NO vmcnt(0) drain.
__device__ __forceinline__ void block_sync() {
    asm volatile("s_waitcnt lgkmcnt(0)" ::: "memory");
    __builtin_amdgcn_s_barrier();
    asm volatile("" ::: "memory");
}

__device__ __forceinline__ half8_t load_w8(const float* p) {
    const float4 a = *(const float4*)p;
    const float4 b = *(const float4*)(p + 4);
    half8_t r;
    r[0] = (_Float16)a.x; r[1] = (_Float16)a.y; r[2] = (_Float16)a.z; r[3] = (_Float16)a.w;
    r[4] = (_Float16)b.x; r[5] = (_Float16)b.y; r[6] = (_Float16)b.z; r[7] = (_Float16)b.w;
    return r;
}

// hrec chunk flush: bufC group fp16 [16w][8m][64gate] -> hout [hh][b][w][128]
__device__ __forceinline__ void flush_chunk(const _Float16* bufCg, _Float16* hout,
                                            int hh0, int b, int dir, int wc0, int t)
{
    const int fm = t >> 5, fwi = (t >> 1) & 15, fhal = t & 1;
    const _Float16* src = bufCg + (fwi * 8 + fm) * 64 + fhal * 32;
    _Float16* dst = hout + ((size_t)(((hh0 + fm) * 8 + b) * 256 + wc0 + fwi) << 7)
                  + dir * 64 + fhal * 32;
    #pragma unroll
    for (int i = 0; i < 4; ++i)
        *(half8_t*)(dst + i * 8) = *(const half8_t*)(src + i * 8);
}

// vrec chunk flush: OutS group f32 [4hh][16w][64ch] -> out f32 [b][ch][hh][w]
__device__ __forceinline__ void vflush(const float* Og, float* outp,
                                       int b, int dir, int w0, int hh0c, int t)
{
    const int ch = t & 63;
    const int hq = t >> 6;            // 0..3 (hh within group)
    float v[16];
    #pragma unroll
    for (int w = 0; w < 16; ++w) v[w] = Og[hq * 1024 + w * 64 + ch];
    float* dst = outp + ((size_t)(b * 128 + dir * 64 + ch) * 128 + hh0c + hq) * 256 + w0;
    #pragma unroll
    for (int i = 0; i < 4; ++i)
        *(float4*)(dst + i * 4) = make_float4(v[i*4], v[i*4+1], v[i*4+2], v[i*4+3]);
}

// ---------------- K0: img transpose to fp16 [b][hh][w][d] ----------------
__global__ __launch_bounds__(256) void k_xpose(const float* __restrict__ img, _Float16* __restrict__ xt)
{
    __shared__ float Ts[64 * 65];
    const int t  = threadIdx.x;
    const int wt = blockIdx.x & 3;
    const int hh = (blockIdx.x >> 2) & 127;
    const int b  = blockIdx.x >> 9;
    {
        const int d  = t >> 2;
        const int wq = (t & 3) * 16;
        const float* p = img + (((size_t)(b * 64 + d) * 128 + hh) * 256 + wt * 64 + wq);
        #pragma unroll
        for (int i = 0; i < 4; ++i) {
            const float4 v = *(const float4*)(p + i * 4);
            Ts[d * 65 + wq + i * 4 + 0] = v.x;
            Ts[d * 65 + wq + i * 4 + 1] = v.y;
            Ts[d * 65 + wq + i * 4 + 2] = v.z;
            Ts[d * 65 + wq + i * 4 + 3] = v.w;
        }
    }
    __syncthreads();
    const int wl = t >> 2;
    const int dq = (t & 3) * 16;
    half8_t o0, o1;
    #pragma unroll
    for (int i = 0; i < 8; ++i) o0[i] = (_Float16)Ts[(dq + i) * 65 + wl];
    #pragma unroll
    for (int i = 0; i < 8; ++i) o1[i] = (_Float16)Ts[(dq + 8 + i) * 65 + wl];
    _Float16* dst = xt + ((size_t)((b * 128 + hh) * 256 + wt * 64 + wl) << 6) + dq;
    *(half8_t*)(dst)     = o0;
    *(half8_t*)(dst + 8) = o1;
}

// ---------------- K1: horizontal biLSTM (compacted gate math) ----------------
// grid 256 = (b(8) x hh-octet(16))(128) x dir(2); block 256 (4 waves).
__global__ __launch_bounds__(256) void k_hrec(
    const _Float16* __restrict__ xt,
    const float* __restrict__ wihf, const float* __restrict__ whhf,
    const float* __restrict__ bif,  const float* __restrict__ bhf,
    const float* __restrict__ wihb, const float* __restrict__ whhb,
    const float* __restrict__ bib,  const float* __restrict__ bhb,
    _Float16* __restrict__ hout)
{
    __shared__ __align__(16) _Float16 Hbuf[2 * 1024];        // h double buffer
    __shared__ __align__(16) _Float16 bufC[2 * 8192];        // 32 KB retime, dbl grp
    const int t   = threadIdx.x;
    const int dir = blockIdx.x & 1;
    const int g   = blockIdx.x >> 1;
    const int b   = g & 7;
    const int hh0 = (g >> 3) * 8;
    const int wv  = t >> 6;
    const int l   = t & 63;
    const float* Wih = dir ? wihb : wihf;
    const float* Whh = dir ? whhb : whhf;
    const float* Bi  = dir ? bib  : bif;
    const float* Bh  = dir ? bhb  : bhf;

    half8_t Bf[4][4];
    float bias[4];
    #pragma unroll
    for (int p = 0; p < 4; ++p) {
        const int gate = p * 64 + wv * 16 + (l & 15);
        bias[p] = Bi[gate] + Bh[gate];
        #pragma unroll
        for (int kt = 0; kt < 4; ++kt) {
            const int k0 = kt * 32 + (l >> 4) * 8;
            const float* src = (kt < 2) ? (Wih + gate * 64 + k0) : (Whh + gate * 64 + (k0 - 64));
            Bf[p][kt] = load_w8(src);
        }
    }
    for (int i = t; i < 2048; i += 256) Hbuf[i] = (_Float16)0.0f;

    const int mrow = l & 7;
    const int ko   = l >> 4;
    const _Float16* xb = xt + (((size_t)(b * 128 + hh0 + mrow) * 256) << 6) + ko * 8;

    const int col = l & 15;
    const int rq  = l >> 4;
    const int jg  = wv * 16 + col;
    const int hpos = (jg >> 5) * 512 + (((jg >> 3) & 3) * 16) * 8 + (jg & 7);
    // compaction: lane owns rows {row0,row1}; hi lanes take r=2,3 of lane l-32
    const int row0 = (rq >= 2) ? ((rq & 1) * 4 + 2) : (rq * 4);
    const int row1 = row0 + 1;
    float c2_[2] = {0.f, 0.f};

    auto wof = [&](int s) { int ss = s < 256 ? s : 255; return dir ? (255 - ss) : ss; };

    half8_t xE0 = *(const half8_t*)(xb + (wof(0) << 6));
    half8_t xE1 = *(const half8_t*)(xb + (wof(0) << 6) + 32);
    half8_t xO0 = *(const half8_t*)(xb + (wof(1) << 6));
    half8_t xO1 = *(const half8_t*)(xb + (wof(1) << 6) + 32);
    f32x4_t accx[4];
    #pragma unroll
    for (int p = 0; p < 4; ++p) {
        f32x4_t a = {bias[p], bias[p], bias[p], bias[p]};
        a = __builtin_amdgcn_mfma_f32_16x16x32_f16(xE0, Bf[p][0], a, 0, 0, 0);
        a = __builtin_amdgcn_mfma_f32_16x16x32_f16(xE1, Bf[p][1], a, 0, 0, 0);
        accx[p] = a;
    }
    xE0 = *(const half8_t*)(xb + (wof(2) << 6));
    xE1 = *(const half8_t*)(xb + (wof(2) << 6) + 32);
    __syncthreads();

    auto body = [&](int s, half8_t& xr0, half8_t& xr1) {
        const int grp = (s >> 4) & 1;
        if ((s & 15) == 0 && s > 0)
            flush_chunk(bufC + (grp ^ 1) * 8192, hout, hh0, b, dir,
                        dir ? (256 - s) : (s - 16), t);

        const int rdo = (s & 1) << 10;
        const half8_t H0 = *(const half8_t*)(Hbuf + rdo + l * 8);
        const half8_t H1 = *(const half8_t*)(Hbuf + rdo + 512 + l * 8);
        f32x4_t acc[4];
        #pragma unroll
        for (int p = 0; p < 4; ++p) {
            f32x4_t a = accx[p];
            a = __builtin_amdgcn_mfma_f32_16x16x32_f16(H0, Bf[p][2], a, 0, 0, 0);
            a = __builtin_amdgcn_mfma_f32_16x16x32_f16(H1, Bf[p][3], a, 0, 0, 0);
            acc[p] = a;
        }
        #pragma unroll
        for (int p = 0; p < 4; ++p) {
            f32x4_t a = {bias[p], bias[p], bias[p], bias[p]};
            a = __builtin_amdgcn_mfma_f32_16x16x32_f16(xr0, Bf[p][0], a, 0, 0, 0);
            a = __builtin_amdgcn_mfma_f32_16x16x32_f16(xr1, Bf[p][1], a, 0, 0, 0);
            accx[p] = a;
        }
        {
            const int wn = wof(s + 3);
            xr0 = *(const half8_t*)(xb + (wn << 6));
            xr1 = *(const half8_t*)(xb + (wn << 6) + 32);
        }
        // compaction: hi lanes receive lo lanes' r=2,3 pre-activations
        float s2[4], s3[4];
        #pragma unroll
        for (int p = 0; p < 4; ++p) {
            s2[p] = __shfl(acc[p][2], l & 31, 64);
            s3[p] = __shfl(acc[p][3], l & 31, 64);
        }
        const bool hihalf = (rq >= 2);
        float e0[4], e1[4];
        #pragma unroll
        for (int p = 0; p < 4; ++p) {
            e0[p] = hihalf ? s2[p] : acc[p][0];
            e1[p] = hihalf ? s3[p] : acc[p][1];
        }
        c2_[0] = sigm(e0[1]) * c2_[0] + sigm(e0[0]) * tanh_(e0[2]);
        const float hv0 = sigm(e0[3]) * tanh_(c2_[0]);
        c2_[1] = sigm(e1[1]) * c2_[1] + sigm(e1[0]) * tanh_(e1[2]);
        const float hv1 = sigm(e1[3]) * tanh_(c2_[1]);

        const int w   = wof(s);
        const int wro = ((s + 1) & 1) << 10;
        Hbuf[wro + hpos + row0 * 8] = (_Float16)hv0;
        Hbuf[wro + hpos + row1 * 8] = (_Float16)hv1;
        bufC[grp * 8192 + ((w & 15) * 8 + row0) * 64 + jg] = (_Float16)hv0;
        bufC[grp * 8192 + ((w & 15) * 8 + row1) * 64 + jg] = (_Float16)hv1;
        block_sync();
    };

    for (int s2i = 0; s2i < 256; s2i += 2) {
        body(s2i,     xO0, xO1);
        body(s2i + 1, xE0, xE1);
    }
    flush_chunk(bufC + 8192, hout, hh0, b, dir, dir ? 0 : 240, t);
}

// ---------------- K2: vertical biLSTM, M=16 + LDS-retimed output ----------------
// grid 256 = (b(8) x w-16-group(16))(128) x dir(2); block 256 (4 waves), 1/CU.
__global__ __launch_bounds__(256) void k_vrec(
    const _Float16* __restrict__ hout,
    const float* __restrict__ wihf, const float* __restrict__ whhf,
    const float* __restrict__ bif,  const float* __restrict__ bhf,
    const float* __restrict__ wihb, const float* __restrict__ whhb,
    const float* __restrict__ bib,  const float* __restrict__ bhb,
    float* __restrict__ outp)
{
    __shared__ __align__(16) _Float16 Hbuf[2 * 1024];     // 4 KB h double buffer
    __shared__ __align__(16) float OutS[2 * 4 * 16 * 64]; // 32 KB out retime, 4-step grps
    const int t   = threadIdx.x;
    const int dir = blockIdx.x & 1;
    const int g   = blockIdx.x >> 1;       // 0..127
    const int b   = g & 7;
    const int w0  = (g >> 3) * 16;         // 16 w-rows per block
    const int wv  = t >> 6;
    const int l   = t & 63;
    const float* Wih = dir ? wihb : wihf;
    const float* Whh = dir ? whhb : whhf;
    const float* Bi  = dir ? bib  : bif;
    const float* Bh  = dir ? bhb  : bhf;

    half8_t Bf[4][6];
    float bias[4];
    #pragma unroll
    for (int p = 0; p < 4; ++p) {
        const int gate = p * 64 + wv * 16 + (l & 15);
        bias[p] = Bi[gate] + Bh[gate];
        #pragma unroll
        for (int kt = 0; kt < 6; ++kt) {
            const int k0 = kt * 32 + (l >> 4) * 8;
            const float* src = (kt < 4) ? (Wih + gate * 128 + k0) : (Whh + gate * 64 + (k0 - 128));
            Bf[p][kt] = load_w8(src);
        }
    }
    for (int i = t; i < 2048; i += 256) Hbuf[i] = (_Float16)0.0f;

    const int mrow = l & 15;               // all 16 rows valid
    const int ko   = l >> 4;
    const _Float16* xb = hout + ((size_t)(b * 256 + w0 + mrow) << 7) + ko * 8;

    float c_[4] = {0.f, 0.f, 0.f, 0.f};
    const int col = l & 15;
    const int rq  = l >> 4;
    const int jg  = wv * 16 + col;
    const int hpos = (jg >> 5) * 512 + (((jg >> 3) & 3) * 16) * 8 + (jg & 7);

    auto hof = [&](int s) { int ss = s < 128 ? s : 127; return dir ? (127 - ss) : ss; };

    half8_t xE[4], xO[4];
    #pragma unroll
    for (int kt = 0; kt < 4; ++kt) {
        xE[kt] = *(const half8_t*)(xb + ((size_t)hof(0) << 18) + kt * 32);
        xO[kt] = *(const half8_t*)(xb + ((size_t)hof(1) << 18) + kt * 32);
    }
    f32x4_t accx[4];
    #pragma unroll
    for (int p = 0; p < 4; ++p) {
        f32x4_t a = {bias[p], bias[p], bias[p], bias[p]};
        #pragma unroll
        for (int kt = 0; kt < 4; ++kt)
            a = __builtin_amdgcn_mfma_f32_16x16x32_f16(xE[kt], Bf[p][kt], a, 0, 0, 0);
        accx[p] = a;
    }
    #pragma unroll
    for (int kt = 0; kt < 4; ++kt)
        xE[kt] = *(const half8_t*)(xb + ((size_t)hof(2) << 18) + kt * 32);
    __syncthreads();

    auto body = [&](int s, half8_t (&xr)[4]) {
        const int grp = (s >> 2) & 1;
        if ((s & 3) == 0 && s > 0)
            vflush(OutS + (grp ^ 1) * 4096, outp, b, dir, w0,
                   dir ? (128 - s) : (s - 4), t);

        const int rdo = (s & 1) << 10;
        const half8_t H0 = *(const half8_t*)(Hbuf + rdo + l * 8);
        const half8_t H1 = *(const half8_t*)(Hbuf + rdo + 512 + l * 8);
        f32x4_t acc[4];
        #pragma unroll
        for (int p = 0; p < 4; ++p) {
            f32x4_t a = accx[p];
            a = __builtin_amdgcn_mfma_f32_16x16x32_f16(H0, Bf[p][4], a, 0, 0, 0);
            a = __builtin_amdgcn_mfma_f32_16x16x32_f16(H1, Bf[p][5], a, 0, 0, 0);
            acc[p] = a;
        }
        #pragma unroll
        for (int p = 0; p < 4; ++p) {
            f32x4_t a = {bias[p], bias[p], bias[p], bias[p]};
            #pragma unroll
            for (int kt = 0; kt < 4; ++kt)
                a = __builtin_amdgcn_mfma_f32_16x16x32_f16(xr[kt], Bf[p][kt], a, 0, 0, 0);
            accx[p] = a;
        }
        {
            const int hn = hof(s + 3);
            #pragma unroll
            for (int kt = 0; kt < 4; ++kt)
                xr[kt] = *(const half8_t*)(xb + ((size_t)hn << 18) + kt * 32);
        }
        float hv[4];
        #pragma unroll
        for (int r = 0; r < 4; ++r) {
            c_[r] = sigm(acc[1][r]) * c_[r] + sigm(acc[0][r]) * tanh_(acc[2][r]);
            hv[r] = sigm(acc[3][r]) * tanh_(c_[r]);
        }
        const int hh  = hof(s);
        const int wro = ((s + 1) & 1) << 10;
        #pragma unroll
        for (int r = 0; r < 4; ++r) {
            const int m = rq * 4 + r;      // 0..15, all valid
            Hbuf[wro + hpos + m * 8] = (_Float16)hv[r];
            OutS[grp * 4096 + (hh & 3) * 1024 + m * 64 + jg] = hv[r];
        }
        block_sync();
    };

    for (int s2i = 0; s2i < 128; s2i += 2) {
        body(s2i,     xO);
        body(s2i + 1, xE);
    }
    vflush(OutS + 4096, outp, b, dir, w0, dir ? 0 : 124, t);
}

extern "C" void kernel_launch(void* const* d_in, const int* in_sizes, int n_in,
                              void* d_out, int out_size, void* d_ws, size_t ws_size,
                              hipStream_t stream)
{
    const float* img   = (const float*)d_in[0];
    const float* hWihF = (const float*)d_in[1];
    const float* hWhhF = (const float*)d_in[2];
    const float* hBiF  = (const float*)d_in[3];
    const float* hBhF  = (const float*)d_in[4];
    const float* hWihB = (const float*)d_in[5];
    const float* hWhhB = (const float*)d_in[6];
    const float* hBiB  = (const float*)d_in[7];
    const float* hBhB  = (const float*)d_in[8];
    const float* vWihF = (const float*)d_in[9];
    const float* vWhhF = (const float*)d_in[10];
    const float* vBiF  = (const float*)d_in[11];
    const float* vBhF  = (const float*)d_in[12];
    const float* vWihB = (const float*)d_in[13];
    const float* vWhhB = (const float*)d_in[14];
    const float* vBiB  = (const float*)d_in[15];
    const float* vBhB  = (const float*)d_in[16];

    _Float16* XT   = (_Float16*)d_ws;                             // 32 MB
    _Float16* HOUT = (_Float16*)((char*)d_ws + (size_t)33554432); // 64 MB

    k_xpose<<<4096, 256, 0, stream>>>(img, XT);
    k_hrec<<<256, 256, 0, stream>>>(XT, hWihF, hWhhF, hBiF, hBhF,
                                    hWihB, hWhhB, hBiB, hBhB, HOUT);
    k_vrec<<<256, 256, 0, stream>>>(HOUT, vWihF, vWhhF, vBiF, vBhF,
                                    vWihB, vWhhB, vBiB, vBhB, (float*)d_out);

    (void)in_sizes; (void)n_in; (void)out_size; (void)ws_size;
}